// Round 1
// 1213.230 us; speedup vs baseline: 1.1144x; 1.1144x over previous
//
#include <hip/hip_runtime.h>
#include <math.h>

// Problem constants
#define B_Q   64
#define K_A   4096
#define DIMV  50257
#define KPAD  50688          // multiple of NK*DT (12*64=768): 50688 = 66*768
#define NK    12             // split-K chunks -> 768 blocks = 3 blocks/CU
#define KCH   4224           // KPAD/NK
#define DT    64             // k depth per LDS stage
#define NSTG  66             // KCH/DT (exact)
#define LR    72             // LDS row stride in bf16 elements (144 B)
#define TN    64             // anchors per block

typedef short bf16x8 __attribute__((ext_vector_type(8)));
typedef float f32x4  __attribute__((ext_vector_type(4)));

static __device__ __forceinline__ unsigned short f2bf(float x) {
    unsigned int u = __builtin_bit_cast(unsigned int, x);
    unsigned int r = u + 0x7FFFu + ((u >> 16) & 1u);   // RTNE
    return (unsigned short)(r >> 16);
}
static __device__ __forceinline__ float bf2f(unsigned short h) {
    unsigned int u = ((unsigned int)h) << 16;
    return __builtin_bit_cast(float, u);
}
// fast ln via v_log_f32; rel err ~2^-21, far below bf16-pair quantization.
// Only used for the self-term (NOT for MFMA inputs).
static __device__ __forceinline__ float fastln(float x) {
    return __log2f(x) * 0.69314718055994531f;
}

// ---------------- query log + hi/lo split ----------------
// grid (KPAD/256, B_Q), block 256  (cold: ~15us, keep precise logf + perfect coalescing)
__global__ void qprep_k(const float* __restrict__ q,
                        unsigned short* __restrict__ qh,
                        unsigned short* __restrict__ ql) {
    int col = blockIdx.x * 256 + threadIdx.x;
    int row = blockIdx.y;
    float x = 0.f;
    if (col < DIMV) x = logf(q[(size_t)row * DIMV + col] + 1e-10f);
    unsigned short h = f2bf(x);
    unsigned short l = f2bf(x - bf2f(h));
    qh[(size_t)row * KPAD + col] = h;
    ql[(size_t)row * KPAD + col] = l;
}

// ---------------- MFMA split-K GEMM + self-term ----------------
// grid (K_A/TN, NK) = (64,12) = 768 blocks, block 256 (4 waves), 3 blocks/CU.
// Double-buffered anchor LDS, 1 barrier/stage, 1-stage register prefetch of
// anchors (fp32) and query A-fragments (bf16 hi/lo straight from L2).
__global__ __launch_bounds__(256, 3)
void gemm_k(const unsigned short* __restrict__ qh_g,
            const unsigned short* __restrict__ ql_g,
            const float* __restrict__ anc,
            float* __restrict__ cpart, float* __restrict__ spart)
{
    __shared__ __align__(16) unsigned short ah_s[2][TN * LR];
    __shared__ __align__(16) unsigned short al_s[2][TN * LR];

    // Bijective XCD-chunk swizzle (768 wg = 8 XCDs x 96): each XCD stays on
    // <=2 query k-chunks (~2.2 MB) so qh/ql remain L2-resident.
    const int F  = blockIdx.x + (K_A / TN) * blockIdx.y;
    const int wg = (F & 7) * 96 + (F >> 3);
    const int c  = wg >> 6;          // k-chunk 0..11
    const int n0 = (wg & 63) * TN;   // anchor tile base

    const int t    = threadIdx.x;
    const int lane = t & 63;
    const int m0   = (t >> 6) * 16;  // wave's query-row base
    const int l15  = lane & 15;
    const int q4   = lane >> 4;

    f32x4 acc[4];
#pragma unroll
    for (int i = 0; i < 4; i++) acc[i] = (f32x4){0.f, 0.f, 0.f, 0.f};
    float sacc[4] = {0.f, 0.f, 0.f, 0.f};

    const int arow = t >> 4;         // 0..15, anchor staging row base
    const int ac4  = (t & 15) * 4;   // anchor staging col (floats)
    const int kb0  = c * KCH;

    // per-lane query fragment pointers (row m0+l15, k-slice q4*8)
    const unsigned short* qph = qh_g + (size_t)(m0 + l15) * KPAD + kb0 + q4 * 8;
    const unsigned short* qpl = ql_g + (size_t)(m0 + l15) * KPAD + kb0 + q4 * 8;

    // ---- stage-0 prefetch (always fully in-bounds: kb0+63 < DIMV) ----
    bf16x8 qfh0 = *(const bf16x8*)(qph);
    bf16x8 qfh1 = *(const bf16x8*)(qph + 32);
    bf16x8 qfl0 = *(const bf16x8*)(qpl);
    bf16x8 qfl1 = *(const bf16x8*)(qpl + 32);
    float4 av[4];
#pragma unroll
    for (int j = 0; j < 4; j++) {
        const float* ap = anc + (size_t)(n0 + arow + 16 * j) * DIMV + kb0 + ac4;
        av[j] = *(const float4*)ap;
    }

#pragma unroll 1
    for (int s = 0; s < NSTG; ++s) {
        const int p = s & 1;
        const bool have_next = (s + 1 < NSTG);

        // ---- issue prefetch for stage s+1 (in flight across convert+MFMA) ----
        bf16x8 nqh0, nqh1, nql0, nql1;
        float4 nv[4];
        if (have_next) {
            const int off = (s + 1) * DT;
            nqh0 = *(const bf16x8*)(qph + off);
            nqh1 = *(const bf16x8*)(qph + off + 32);
            nql0 = *(const bf16x8*)(qpl + off);
            nql1 = *(const bf16x8*)(qpl + off + 32);
            const int kbn = kb0 + off;
            const bool fullN = (kbn + DT <= DIMV);
#pragma unroll
            for (int j = 0; j < 4; j++) {
                const float* ap = anc + (size_t)(n0 + arow + 16 * j) * DIMV + kbn + ac4;
                if (fullN) {
                    nv[j] = *(const float4*)ap;
                } else {
                    const int d = kbn + ac4;
                    nv[j].x = (d + 0 < DIMV) ? ap[0] : 0.f;
                    nv[j].y = (d + 1 < DIMV) ? ap[1] : 0.f;
                    nv[j].z = (d + 2 < DIMV) ? ap[2] : 0.f;
                    nv[j].w = (d + 3 < DIMV) ? ap[3] : 0.f;
                }
            }
        }

        // ---- convert current anchors -> LDS buf p, accumulate self-term ----
#pragma unroll
        for (int j = 0; j < 4; j++) {
            const float a0 = av[j].x, a1 = av[j].y, a2 = av[j].z, a3 = av[j].w;
            sacc[j] += a0 * fastln(a0 + 1e-10f) + a1 * fastln(a1 + 1e-10f)
                     + a2 * fastln(a2 + 1e-10f) + a3 * fastln(a3 + 1e-10f);
            ushort4 hv, lv;
            hv.x = f2bf(a0); lv.x = f2bf(a0 - bf2f(hv.x));
            hv.y = f2bf(a1); lv.y = f2bf(a1 - bf2f(hv.y));
            hv.z = f2bf(a2); lv.z = f2bf(a2 - bf2f(hv.z));
            hv.w = f2bf(a3); lv.w = f2bf(a3 - bf2f(hv.w));
            const int r = arow + 16 * j;
            *(ushort4*)(&ah_s[p][r * LR + ac4]) = hv;
            *(ushort4*)(&al_s[p][r * LR + ac4]) = lv;
        }
        __syncthreads();
        // (one barrier/stage: between this barrier and the next, waves only
        //  read buf p and write buf p^1 -> no cross-wave hazard)

        // ---- MFMA over buf p: 2 k-steps x 4 anchor tiles x 3 terms ----
        {
            const int k0 = q4 * 8;
#pragma unroll
            for (int tl = 0; tl < 4; tl++) {
                bf16x8 b_h = *(const bf16x8*)(&ah_s[p][(16 * tl + l15) * LR + k0]);
                bf16x8 b_l = *(const bf16x8*)(&al_s[p][(16 * tl + l15) * LR + k0]);
                acc[tl] = __builtin_amdgcn_mfma_f32_16x16x32_bf16(qfh0, b_h, acc[tl], 0, 0, 0);
                acc[tl] = __builtin_amdgcn_mfma_f32_16x16x32_bf16(qfh0, b_l, acc[tl], 0, 0, 0);
                acc[tl] = __builtin_amdgcn_mfma_f32_16x16x32_bf16(qfl0, b_h, acc[tl], 0, 0, 0);
            }
#pragma unroll
            for (int tl = 0; tl < 4; tl++) {
                bf16x8 b_h = *(const bf16x8*)(&ah_s[p][(16 * tl + l15) * LR + 32 + k0]);
                bf16x8 b_l = *(const bf16x8*)(&al_s[p][(16 * tl + l15) * LR + 32 + k0]);
                acc[tl] = __builtin_amdgcn_mfma_f32_16x16x32_bf16(qfh1, b_h, acc[tl], 0, 0, 0);
                acc[tl] = __builtin_amdgcn_mfma_f32_16x16x32_bf16(qfh1, b_l, acc[tl], 0, 0, 0);
                acc[tl] = __builtin_amdgcn_mfma_f32_16x16x32_bf16(qfl1, b_h, acc[tl], 0, 0, 0);
            }
        }

        if (have_next) {
#pragma unroll
            for (int j = 0; j < 4; j++) av[j] = nv[j];
            qfh0 = nqh0; qfh1 = nqh1; qfl0 = nql0; qfl1 = nql1;
        }
    }

    // ---- write cross partials (C/D layout: col=lane&15, row=quad*4+reg) ----
#pragma unroll
    for (int tl = 0; tl < 4; tl++)
#pragma unroll
        for (int r = 0; r < 4; r++) {
            const int m = m0 + q4 * 4 + r;
            const int n = n0 + 16 * tl + l15;
            cpart[((size_t)(c * B_Q + m)) * K_A + n] = acc[tl][r];
        }

    // ---- self-term: reduce over the 16 threads sharing each staged row ----
#pragma unroll
    for (int j = 0; j < 4; j++) {
        float sum = sacc[j];
#pragma unroll
        for (int m = 1; m <= 8; m <<= 1) sum += __shfl_xor(sum, m, 64);
        if ((t & 15) == 0) spart[c * K_A + n0 + arow + 16 * j] = sum;
    }
}

// ---------------- top-8 + majority vote ----------------
// grid B_Q, block 256 (4 waves). Wave-shuffle min-reduce: 2 barriers/iter.
__global__ void topk_k(const float* __restrict__ cpart, const float* __restrict__ spart,
                       const int* __restrict__ labels, int* __restrict__ out)
{
    __shared__ float vals[K_A];
    __shared__ float wmv[4];
    __shared__ int   wmi[4];
    __shared__ int   chosen[8];

    const int b = blockIdx.x;
    const int t = threadIdx.x;
    const int w = t >> 6, lane = t & 63;

    for (int k = t; k < K_A; k += 256) {
        float s = 0.f, cr = 0.f;
#pragma unroll
        for (int c = 0; c < NK; c++) {
            s  += spart[c * K_A + k];
            cr += cpart[(size_t)(c * B_Q + b) * K_A + k];
        }
        vals[k] = s - cr;   // unscaled kl (monotonic)
    }
    __syncthreads();

    for (int it = 0; it < 8; it++) {
        float mv = INFINITY; int mi = 1 << 30;
        for (int k = t; k < K_A; k += 256) {
            float v = vals[k];
            if (v < mv) { mv = v; mi = k; }   // strided scan keeps smallest idx on ties
        }
#pragma unroll
        for (int m = 1; m <= 32; m <<= 1) {
            float v2 = __shfl_xor(mv, m, 64);
            int   i2 = __shfl_xor(mi, m, 64);
            if (v2 < mv || (v2 == mv && i2 < mi)) { mv = v2; mi = i2; }
        }
        if (lane == 0) { wmv[w] = mv; wmi[w] = mi; }
        __syncthreads();
        if (t == 0) {
            float bv = wmv[0]; int bi = wmi[0];
#pragma unroll
            for (int i = 1; i < 4; i++)
                if (wmv[i] < bv || (wmv[i] == bv && wmi[i] < bi)) { bv = wmv[i]; bi = wmi[i]; }
            chosen[it] = bi;
            vals[bi] = INFINITY;
        }
        __syncthreads();
    }

    if (t == 0) {
        int cnt1 = 0;
#pragma unroll
        for (int it = 0; it < 8; it++) cnt1 += labels[chosen[it]];
        out[b] = (cnt1 >= 5) ? 1 : 0;   // argmax([cnt0,cnt1]), tie -> 0
    }
}

extern "C" void kernel_launch(void* const* d_in, const int* in_sizes, int n_in,
                              void* d_out, int out_size, void* d_ws, size_t ws_size,
                              hipStream_t stream) {
    const float* query  = (const float*)d_in[0];
    const float* anchor = (const float*)d_in[1];
    const int*   labels = (const int*)d_in[2];
    int* out = (int*)d_out;

    char* ws = (char*)d_ws;
    unsigned short* qh = (unsigned short*)ws;                        // 64*50688*2 = 6,488,064
    unsigned short* ql = (unsigned short*)(ws + 6488064);            // 6,488,064
    float* cpart = (float*)(ws + 12976128);                          // 12*64*4096*4 = 12,582,912
    float* spart = (float*)(ws + 12976128 + 12582912);               // 12*4096*4 = 196,608

    qprep_k<<<dim3(KPAD / 256, B_Q), 256, 0, stream>>>(query, qh, ql);
    gemm_k<<<dim3(K_A / TN, NK), 256, 0, stream>>>(qh, ql, anchor, cpart, spart);
    topk_k<<<B_Q, 256, 0, stream>>>(cpart, spart, labels, out);
}